// Round 1
// baseline (1270.296 us; speedup 1.0000x reference)
//
#include <hip/hip_runtime.h>

// ---------- types & helpers ----------
using f32x4   = __attribute__((ext_vector_type(4))) float;
using bf16x8  = __attribute__((ext_vector_type(8))) short;
using ushort4_t = __attribute__((ext_vector_type(4))) unsigned short;
using uint4_t   = __attribute__((ext_vector_type(4))) unsigned int;

__device__ __forceinline__ unsigned short f2bf(float f) {
    unsigned u = __builtin_bit_cast(unsigned, f);
    u += 0x7fffu + ((u >> 16) & 1u);   // RNE
    return (unsigned short)(u >> 16);
}

__device__ __forceinline__ float wave_sum(float v) {
#pragma unroll
    for (int off = 32; off > 0; off >>= 1) v += __shfl_xor(v, off, 64);
    return v;
}
__device__ __forceinline__ float wave_max(float v) {
#pragma unroll
    for (int off = 32; off > 0; off >>= 1) v = fmaxf(v, __shfl_xor(v, off, 64));
    return v;
}

// ---------- weight pack (transpose -> bf16, [N][K] row-major) ----------
__global__ void pack_w(const float* __restrict__ Wc, const float* __restrict__ Wi,
                       unsigned short* __restrict__ Wp) {
    // grid (1536, 8), block 256 : n = bx, k = by*256+tid
    int n = blockIdx.x, k = blockIdx.y * 256 + threadIdx.x;
    float v = (n < 768) ? Wc[(size_t)k * 768 + n] : Wi[(size_t)k * 768 + (n - 768)];
    Wp[(size_t)n * 2048 + k] = f2bf(v);
}

__global__ void pack_wq(const float* __restrict__ Wq, unsigned short* __restrict__ Wqt) {
    // grid (768, 3), block 256
    int n = blockIdx.x, k = blockIdx.y * 256 + threadIdx.x;
    Wqt[(size_t)n * 768 + k] = f2bf(Wq[(size_t)k * 768 + n]);
}

// ---------- bf16 MFMA GEMM:  C[M][N] = A_f32[M][K] @ Bt[N][K]^T + bias ----------
// 128x128 tile, BK=32, 4 waves, reg-staged LDS with inline f32->bf16 cvt for A.
__global__ __launch_bounds__(256) void gemm_bf16(
    const float* __restrict__ A, const unsigned short* __restrict__ Bt,
    const float* __restrict__ bias0, const float* __restrict__ bias1, int nsplit,
    float* __restrict__ C, int M, int N, int K)
{
    const int tid = threadIdx.x, lane = tid & 63, wid = tid >> 6;
    const int m0 = blockIdx.x * 128, n0 = blockIdx.y * 128;
    // row stride 40 shorts (80B): 8-row bank rotation -> ~2-way (free) on ds_read_b128
    __shared__ unsigned short Al[128 * 40];
    __shared__ unsigned short Bl[128 * 40];

    f32x4 acc[4][4];
#pragma unroll
    for (int i = 0; i < 4; ++i)
#pragma unroll
        for (int j = 0; j < 4; ++j) acc[i][j] = (f32x4){0.f, 0.f, 0.f, 0.f};

    const int wm_ = (wid >> 1) * 64, wn_ = (wid & 1) * 64;
    const int fr = lane & 15, fk = (lane >> 4) * 8;

    for (int k0 = 0; k0 < K; k0 += 32) {
        __syncthreads();
        // stage A: 128 rows x 32 f32 -> bf16 (1024 float4 chunks)
#pragma unroll
        for (int it = 0; it < 4; ++it) {
            int idx = tid + it * 256;
            int row = idx >> 3, c4 = idx & 7;
            float4 v = *(const float4*)(A + (size_t)(m0 + row) * K + k0 + c4 * 4);
            ushort4_t h;
            h.x = f2bf(v.x); h.y = f2bf(v.y); h.z = f2bf(v.z); h.w = f2bf(v.w);
            *(ushort4_t*)&Al[row * 40 + c4 * 4] = h;
        }
        // stage B: 128 rows x 32 bf16 (512 16B chunks)
#pragma unroll
        for (int it = 0; it < 2; ++it) {
            int idx = tid + it * 256;
            int row = idx >> 2, c4 = idx & 3;
            uint4_t v = *(const uint4_t*)(Bt + (size_t)(n0 + row) * K + k0 + c4 * 8);
            *(uint4_t*)&Bl[row * 40 + c4 * 8] = v;
        }
        __syncthreads();

        bf16x8 af[4], bfr[4];
#pragma unroll
        for (int i = 0; i < 4; ++i) af[i]  = *(const bf16x8*)&Al[(wm_ + i * 16 + fr) * 40 + fk];
#pragma unroll
        for (int j = 0; j < 4; ++j) bfr[j] = *(const bf16x8*)&Bl[(wn_ + j * 16 + fr) * 40 + fk];
#pragma unroll
        for (int i = 0; i < 4; ++i)
#pragma unroll
            for (int j = 0; j < 4; ++j)
                acc[i][j] = __builtin_amdgcn_mfma_f32_16x16x32_bf16(af[i], bfr[j], acc[i][j], 0, 0, 0);
    }

    // epilogue: C = acc + bias   (C/D layout: col = lane&15, row = (lane>>4)*4 + r)
#pragma unroll
    for (int j = 0; j < 4; ++j) {
        int col = n0 + wn_ + j * 16 + (lane & 15);
        float bs = (col < nsplit) ? bias0[col] : bias1[col - nsplit];
#pragma unroll
        for (int i = 0; i < 4; ++i) {
            int rowb = m0 + wm_ + i * 16 + (lane >> 4) * 4;
#pragma unroll
            for (int r = 0; r < 4; ++r)
                C[(size_t)(rowb + r) * N + col] = acc[i][j][r] + bs;
        }
    }
}

// ---------- wm kernel: wm[b,t,n] = relu(LN_n( ques_feat[b,t,:] . img_corr[b,n,:] )) ----------
__global__ __launch_bounds__(256) void wm_kernel(
    const float* __restrict__ qf_g, const float* __restrict__ imgCE,
    const float* __restrict__ g1, const float* __restrict__ b1,
    float* __restrict__ wm_g)
{
    const int b = blockIdx.x, tid = threadIdx.x, lane = tid & 63, wid = tid >> 6;
    __shared__ float qf[14 * 768];
    __shared__ float wmr[14][100];

    const float4* src = (const float4*)(qf_g + (size_t)b * 14 * 768);
    for (int i = tid; i < 14 * 768 / 4; i += 256) ((float4*)qf)[i] = src[i];
    __syncthreads();

    for (int n = wid; n < 100; n += 4) {
        const float* row = imgCE + ((size_t)b * 100 + n) * 1536;  // img_corr half
        float r[12];
#pragma unroll
        for (int j = 0; j < 12; ++j) r[j] = row[lane + 64 * j];
        for (int t = 0; t < 14; ++t) {
            const float* q = qf + t * 768;
            float s = 0.f;
#pragma unroll
            for (int j = 0; j < 12; ++j) s = fmaf(r[j], q[lane + 64 * j], s);
            s = wave_sum(s);
            if (lane == 0) wmr[t][n] = s;
        }
    }
    __syncthreads();

    for (int t = wid; t < 14; t += 4) {
        float x0 = wmr[t][lane];                                   // lane < 64 < 100
        float x1 = (lane + 64 < 100) ? wmr[t][lane + 64] : 0.f;
        float s = wave_sum(x0 + x1);
        float q = wave_sum(x0 * x0 + x1 * x1);
        float mu = s * (1.f / 100.f);
        float var = q * (1.f / 100.f) - mu * mu;
        float rs = rsqrtf(var + 1e-3f);
        float* dst = wm_g + ((size_t)b * 14 + t) * 100;
        {
            float v = (x0 - mu) * rs * g1[lane] + b1[lane];
            dst[lane] = v > 0.f ? v : 0.f;
        }
        if (lane + 64 < 100) {
            float v = (x1 - mu) * rs * g1[lane + 64] + b1[lane + 64];
            dst[lane + 64] = v > 0.f ? v : 0.f;
        }
    }
}

// ---------- ques path: transform_img + qe -> LN -> relu -> @wqa -> LN_T -> softmax -> @ques_feat ----------
__global__ __launch_bounds__(256) void ques_kernel(
    const float* __restrict__ qf_g, const float* __restrict__ qe_g,
    const float* __restrict__ imgCE, const float* __restrict__ wm_g,
    const float* __restrict__ g2, const float* __restrict__ b2,
    const float* __restrict__ g3, const float* __restrict__ b3,
    const float* __restrict__ wqa, const float* __restrict__ bqa,
    float* __restrict__ out_q)
{
    const int b = blockIdx.x, tid = threadIdx.x, lane = tid & 63, wid = tid >> 6;
    __shared__ float qe[14 * 768];
    __shared__ float wm[14 * 100];
    __shared__ float red[4][28];
    __shared__ float mu_s[14], rs_s[14], qa_s[14], qw_s[14];

    {
        const float4* src = (const float4*)(qe_g + (size_t)b * 14 * 768);
        for (int i = tid; i < 14 * 768 / 4; i += 256) ((float4*)qe)[i] = src[i];
        const float* ws = wm_g + (size_t)b * 1400;
        for (int i = tid; i < 1400; i += 256) wm[i] = ws[i];
    }
    __syncthreads();

    float a0[14], a1[14], a2[14];
#pragma unroll
    for (int t = 0; t < 14; ++t) { a0[t] = 0.f; a1[t] = 0.f; a2[t] = 0.f; }

    const float* ie_base = imgCE + (size_t)b * 100 * 1536 + 768;  // img_embed half
    for (int n = 0; n < 100; ++n) {
        const float* ie = ie_base + (size_t)n * 1536;
        float e0 = ie[tid], e1 = ie[tid + 256], e2 = ie[tid + 512];
#pragma unroll
        for (int t = 0; t < 14; ++t) {
            float w = wm[t * 100 + n];
            a0[t] = fmaf(w, e0, a0[t]); a1[t] = fmaf(w, e1, a1[t]); a2[t] = fmaf(w, e2, a2[t]);
        }
    }
#pragma unroll
    for (int t = 0; t < 14; ++t) {
        a0[t] += qe[t * 768 + tid];
        a1[t] += qe[t * 768 + tid + 256];
        a2[t] += qe[t * 768 + tid + 512];
    }
    // LN stats over H=768 per t
#pragma unroll
    for (int t = 0; t < 14; ++t) {
        float s = wave_sum(a0[t] + a1[t] + a2[t]);
        float q = wave_sum(a0[t] * a0[t] + a1[t] * a1[t] + a2[t] * a2[t]);
        if (lane == 0) { red[wid][t] = s; red[wid][14 + t] = q; }
    }
    __syncthreads();
    if (tid < 14) {
        float s = red[0][tid] + red[1][tid] + red[2][tid] + red[3][tid];
        float q = red[0][14 + tid] + red[1][14 + tid] + red[2][14 + tid] + red[3][14 + tid];
        float mu = s * (1.f / 768.f);
        float var = q * (1.f / 768.f) - mu * mu;
        mu_s[tid] = mu; rs_s[tid] = rsqrtf(var + 1e-3f);
    }
    __syncthreads();

    float ga = g2[tid], ba = b2[tid], gb = g2[tid + 256], bb = b2[tid + 256],
          gc = g2[tid + 512], bc_ = b2[tid + 512];
    float w0 = wqa[tid], w1 = wqa[tid + 256], w2 = wqa[tid + 512];
#pragma unroll
    for (int t = 0; t < 14; ++t) {
        float mu = mu_s[t], rs = rs_s[t];
        float v0 = fmaxf((a0[t] - mu) * rs * ga + ba, 0.f);
        float v1 = fmaxf((a1[t] - mu) * rs * gb + bb, 0.f);
        float v2 = fmaxf((a2[t] - mu) * rs * gc + bc_, 0.f);
        float p = wave_sum(v0 * w0 + v1 * w1 + v2 * w2);
        if (lane == 0) red[wid][t] = p;
    }
    __syncthreads();
    if (tid < 14) qa_s[tid] = red[0][tid] + red[1][tid] + red[2][tid] + red[3][tid] + bqa[0];
    __syncthreads();
    if (tid == 0) {
        float s = 0.f;
        for (int t = 0; t < 14; ++t) s += qa_s[t];
        float mu = s * (1.f / 14.f);
        float q = 0.f;
        for (int t = 0; t < 14; ++t) { float d = qa_s[t] - mu; q += d * d; }
        float rs = rsqrtf(q * (1.f / 14.f) + 1e-3f);
        float e[14], mx = -1e30f;
        for (int t = 0; t < 14; ++t) { e[t] = (qa_s[t] - mu) * rs * g3[t] + b3[t]; mx = fmaxf(mx, e[t]); }
        float se = 0.f;
        for (int t = 0; t < 14; ++t) { e[t] = expf(e[t] - mx); se += e[t]; }
        float inv = 1.f / se;
        for (int t = 0; t < 14; ++t) qw_s[t] = e[t] * inv;
    }
    __syncthreads();

    const float* qf = qf_g + (size_t)b * 14 * 768;
#pragma unroll
    for (int c = 0; c < 3; ++c) {
        int h = tid + c * 256;
        float o = 0.f;
#pragma unroll
        for (int t = 0; t < 14; ++t) o = fmaf(qw_s[t], qf[t * 768 + h], o);
        out_q[(size_t)b * 768 + h] = o;
    }
}

// ---------- img path: transform_ques + img_embed -> LN -> relu -> @wia -> LN_N -> softmax -> @img_feat ----------
__global__ __launch_bounds__(256) void img_kernel(
    const float* __restrict__ img_feat, const float* __restrict__ qe_g,
    const float* __restrict__ imgCE, const float* __restrict__ wm_g,
    const float* __restrict__ g4, const float* __restrict__ b4,
    const float* __restrict__ g5, const float* __restrict__ b5,
    const float* __restrict__ wia, const float* __restrict__ bia,
    float* __restrict__ out_i)
{
    const int b = blockIdx.x, tid = threadIdx.x, lane = tid & 63, wid = tid >> 6;
    __shared__ float qe[14 * 768];
    __shared__ float wm[14 * 100];
    __shared__ float red[4][20];
    __shared__ float mu_s[10], rs_s[10];
    __shared__ float ia_s[100], iw_s[100];

    {
        const float4* src = (const float4*)(qe_g + (size_t)b * 14 * 768);
        for (int i = tid; i < 14 * 768 / 4; i += 256) ((float4*)qe)[i] = src[i];
        const float* ws = wm_g + (size_t)b * 1400;
        for (int i = tid; i < 1400; i += 256) wm[i] = ws[i];
    }
    __syncthreads();

    float g4a = g4[tid], b4a = b4[tid], g4b = g4[tid + 256], b4b = b4[tid + 256],
          g4c = g4[tid + 512], b4c = b4[tid + 512];
    float wa = wia[tid], wb = wia[tid + 256], wc_ = wia[tid + 512];

    for (int g = 0; g < 10; ++g) {
        float t0[10], t1[10], t2[10];
#pragma unroll
        for (int i = 0; i < 10; ++i) { t0[i] = 0.f; t1[i] = 0.f; t2[i] = 0.f; }
#pragma unroll
        for (int t = 0; t < 14; ++t) {
            float q0 = qe[t * 768 + tid], q1 = qe[t * 768 + tid + 256], q2 = qe[t * 768 + tid + 512];
#pragma unroll
            for (int i = 0; i < 10; ++i) {
                float w = wm[t * 100 + g * 10 + i];
                t0[i] = fmaf(w, q0, t0[i]); t1[i] = fmaf(w, q1, t1[i]); t2[i] = fmaf(w, q2, t2[i]);
            }
        }
#pragma unroll
        for (int i = 0; i < 10; ++i) {
            const float* ie = imgCE + ((size_t)b * 100 + g * 10 + i) * 1536 + 768;
            t0[i] += ie[tid]; t1[i] += ie[tid + 256]; t2[i] += ie[tid + 512];
            float s = wave_sum(t0[i] + t1[i] + t2[i]);
            float q = wave_sum(t0[i] * t0[i] + t1[i] * t1[i] + t2[i] * t2[i]);
            if (lane == 0) { red[wid][i] = s; red[wid][10 + i] = q; }
        }
        __syncthreads();
        if (tid < 10) {
            float s = red[0][tid] + red[1][tid] + red[2][tid] + red[3][tid];
            float q = red[0][10 + tid] + red[1][10 + tid] + red[2][10 + tid] + red[3][10 + tid];
            float mu = s * (1.f / 768.f);
            float var = q * (1.f / 768.f) - mu * mu;
            mu_s[tid] = mu; rs_s[tid] = rsqrtf(var + 1e-3f);
        }
        __syncthreads();
#pragma unroll
        for (int i = 0; i < 10; ++i) {
            float mu = mu_s[i], rs = rs_s[i];
            float v0 = fmaxf((t0[i] - mu) * rs * g4a + b4a, 0.f);
            float v1 = fmaxf((t1[i] - mu) * rs * g4b + b4b, 0.f);
            float v2 = fmaxf((t2[i] - mu) * rs * g4c + b4c, 0.f);
            float p = wave_sum(v0 * wa + v1 * wb + v2 * wc_);
            if (lane == 0) red[wid][i] = p;
        }
        __syncthreads();
        if (tid < 10) ia_s[g * 10 + tid] = red[0][tid] + red[1][tid] + red[2][tid] + red[3][tid] + bia[0];
        __syncthreads();
    }

    // LN over N=100 + softmax (wave 0)
    if (wid == 0) {
        float x0 = ia_s[lane];
        float x1 = (lane + 64 < 100) ? ia_s[lane + 64] : 0.f;
        float s = wave_sum(x0 + x1);
        float q = wave_sum(x0 * x0 + x1 * x1);
        float mu = s * 0.01f;
        float var = q * 0.01f - mu * mu;
        float rs = rsqrtf(var + 1e-3f);
        float v0 = (x0 - mu) * rs * g5[lane] + b5[lane];
        float v1 = (lane + 64 < 100) ? (x1 - mu) * rs * g5[lane + 64] + b5[lane + 64] : -1e30f;
        float mx = wave_max(fmaxf(v0, v1));
        float e0 = expf(v0 - mx);
        float e1 = (lane + 64 < 100) ? expf(v1 - mx) : 0.f;
        float se = wave_sum(e0 + e1);
        float inv = 1.f / se;
        iw_s[lane] = e0 * inv;
        if (lane + 64 < 100) iw_s[lane + 64] = e1 * inv;
    }
    __syncthreads();

    // img_atten_feat = sum_n iw[n] * img_feat[b,n,:]
    const float* imf = img_feat + (size_t)b * 100 * 2048;
#pragma unroll
    for (int c = 0; c < 2; ++c) {
        int col = tid + c * 256;  // float4 index, 512 per row
        float4 acc = {0.f, 0.f, 0.f, 0.f};
        for (int n = 0; n < 100; ++n) {
            float4 v = ((const float4*)(imf + (size_t)n * 2048))[col];
            float w = iw_s[n];
            acc.x = fmaf(w, v.x, acc.x); acc.y = fmaf(w, v.y, acc.y);
            acc.z = fmaf(w, v.z, acc.z); acc.w = fmaf(w, v.w, acc.w);
        }
        ((float4*)(out_i + (size_t)b * 2048))[col] = acc;
    }
}

// ---------- launch ----------
extern "C" void kernel_launch(void* const* d_in, const int* in_sizes, int n_in,
                              void* d_out, int out_size, void* d_ws, size_t ws_size,
                              hipStream_t stream)
{
    const float* img_feat = (const float*)d_in[0];
    const float* ques_feat = (const float*)d_in[1];
    const float* Wc = (const float*)d_in[2];
    const float* bc = (const float*)d_in[3];
    const float* Wq = (const float*)d_in[4];
    const float* bq = (const float*)d_in[5];
    const float* Wi = (const float*)d_in[6];
    const float* bi = (const float*)d_in[7];
    const float* wqa = (const float*)d_in[8];
    const float* bqa = (const float*)d_in[9];
    const float* wia = (const float*)d_in[10];
    const float* bia = (const float*)d_in[11];
    const float* g1 = (const float*)d_in[12]; const float* b1 = (const float*)d_in[13];
    const float* g2 = (const float*)d_in[14]; const float* b2 = (const float*)d_in[15];
    const float* g3 = (const float*)d_in[16]; const float* b3 = (const float*)d_in[17];
    const float* g4 = (const float*)d_in[18]; const float* b4 = (const float*)d_in[19];
    const float* g5 = (const float*)d_in[20]; const float* b5 = (const float*)d_in[21];

    // workspace layout (bytes)
    const size_t OFF_WP   = 0;                       // 1536*2048*2   = 6,291,456
    const size_t OFF_WQT  = 6291456;                 // 768*768*2     = 1,179,648
    const size_t OFF_IMG  = 7471104;                 // 51200*1536*4  = 314,572,800
    const size_t OFF_QE   = OFF_IMG + 314572800;     // 7168*768*4    = 22,020,096
    const size_t OFF_WM   = OFF_QE + 22020096;       // 512*14*100*4  = 2,867,200
    const size_t NEED     = OFF_WM + 2867200;
    if (ws_size < NEED) return;

    char* ws = (char*)d_ws;
    unsigned short* Wp  = (unsigned short*)(ws + OFF_WP);
    unsigned short* Wqt = (unsigned short*)(ws + OFF_WQT);
    float* imgCE = (float*)(ws + OFF_IMG);
    float* qe    = (float*)(ws + OFF_QE);
    float* wm    = (float*)(ws + OFF_WM);

    float* out_img = (float*)d_out;                   // [512][2048]
    float* out_q   = (float*)d_out + 512 * 2048;      // [512][768]

    hipLaunchKernelGGL(pack_w,  dim3(1536, 8), dim3(256), 0, stream, Wc, Wi, Wp);
    hipLaunchKernelGGL(pack_wq, dim3(768, 3),  dim3(256), 0, stream, Wq, Wqt);

    // imgCE = img_feat @ [Wc | Wi] + [bc | bi]   (M=51200, N=1536, K=2048)
    hipLaunchKernelGGL(gemm_bf16, dim3(400, 12), dim3(256), 0, stream,
                       img_feat, Wp, bc, bi, 768, imgCE, 51200, 1536, 2048);
    // qe = ques_feat @ Wq + bq                   (M=7168, N=768, K=768)
    hipLaunchKernelGGL(gemm_bf16, dim3(56, 6), dim3(256), 0, stream,
                       ques_feat, Wqt, bq, bq, 768, qe, 7168, 768, 768);

    hipLaunchKernelGGL(wm_kernel, dim3(512), dim3(256), 0, stream,
                       ques_feat, imgCE, g1, b1, wm);
    hipLaunchKernelGGL(ques_kernel, dim3(512), dim3(256), 0, stream,
                       ques_feat, qe, imgCE, wm, g2, b2, g3, b3, wqa, bqa, out_q);
    hipLaunchKernelGGL(img_kernel, dim3(512), dim3(256), 0, stream,
                       img_feat, qe, imgCE, wm, g4, b4, g5, b5, wia, bia, out_img);
}

// Round 2
// 974.843 us; speedup vs baseline: 1.3031x; 1.3031x over previous
//
#include <hip/hip_runtime.h>

// ---------- types & helpers ----------
using f32x4     = __attribute__((ext_vector_type(4))) float;
using bf16x8    = __attribute__((ext_vector_type(8))) short;
using ushort4_t = __attribute__((ext_vector_type(4))) unsigned short;
using ushort8_t = __attribute__((ext_vector_type(8))) unsigned short;
using uint4_t   = __attribute__((ext_vector_type(4))) unsigned int;

__device__ __forceinline__ unsigned short f2bf(float f) {
    unsigned u = __builtin_bit_cast(unsigned, f);
    u += 0x7fffu + ((u >> 16) & 1u);   // RNE
    return (unsigned short)(u >> 16);
}

__device__ __forceinline__ float wave_sum(float v) {
#pragma unroll
    for (int off = 32; off > 0; off >>= 1) v += __shfl_xor(v, off, 64);
    return v;
}
__device__ __forceinline__ float wave_max(float v) {
#pragma unroll
    for (int off = 32; off > 0; off >>= 1) v = fmaxf(v, __shfl_xor(v, off, 64));
    return v;
}

#define GLP(p)  ((const __attribute__((address_space(1))) void*)(p))
#define LDSP(p) ((__attribute__((address_space(3))) void*)(p))

// ---------- f32 -> bf16 bulk convert (8 elems/thread/iter) ----------
__global__ __launch_bounds__(256) void cvt_bf16(const float* __restrict__ in,
                                                unsigned short* __restrict__ out, long n8) {
    long i = (long)blockIdx.x * 256 + threadIdx.x;
    long stride = (long)gridDim.x * 256;
    for (; i < n8; i += stride) {
        const float4* p = (const float4*)(in + i * 8);
        float4 a = p[0], b = p[1];
        ushort8_t v;
        v[0] = f2bf(a.x); v[1] = f2bf(a.y); v[2] = f2bf(a.z); v[3] = f2bf(a.w);
        v[4] = f2bf(b.x); v[5] = f2bf(b.y); v[6] = f2bf(b.z); v[7] = f2bf(b.w);
        *(ushort8_t*)(out + i * 8) = v;
    }
}

// ---------- weight pack (transpose -> bf16, [N][K] row-major) ----------
__global__ void pack_w(const float* __restrict__ Wc, const float* __restrict__ Wi,
                       unsigned short* __restrict__ Wp) {
    int n = blockIdx.x, k = blockIdx.y * 256 + threadIdx.x;
    float v = (n < 768) ? Wc[(size_t)k * 768 + n] : Wi[(size_t)k * 768 + (n - 768)];
    Wp[(size_t)n * 2048 + k] = f2bf(v);
}

__global__ void pack_wq(const float* __restrict__ Wq, unsigned short* __restrict__ Wqt) {
    int n = blockIdx.x, k = blockIdx.y * 256 + threadIdx.x;
    Wqt[(size_t)n * 768 + k] = f2bf(Wq[(size_t)k * 768 + n]);
}

// ---------- m97-style bf16 GEMM: C[M][N] = Abf[M][K] @ Bt[N][K]^T + bias ----------
// 128x128 tile, BK=32, 4 waves, global_load_lds width-16 staging, linear LDS.
// grid: (N/128, M/128)  -> n-fastest for A-tile L2 reuse.
__global__ __launch_bounds__(256) void gemm_lds(
    const unsigned short* __restrict__ Abf, const unsigned short* __restrict__ Bt,
    const float* __restrict__ bias0, const float* __restrict__ bias1, int nsplit,
    float* __restrict__ C, int M, int N, int K)
{
    const int tid = threadIdx.x, lane = tid & 63, wid = tid >> 6;
    const int n0 = blockIdx.x * 128, m0 = blockIdx.y * 128;
    __shared__ unsigned short Al[128 * 32];   // linear, stride 32 shorts (64B)
    __shared__ unsigned short Bl[128 * 32];

    f32x4 acc[4][4];
#pragma unroll
    for (int i = 0; i < 4; ++i)
#pragma unroll
        for (int j = 0; j < 4; ++j) acc[i][j] = (f32x4){0.f, 0.f, 0.f, 0.f};

    const int wm_ = (wid >> 1) * 64, wn_ = (wid & 1) * 64;
    const int fr = lane & 15, fk = (lane >> 4) * 8;

    for (int k0 = 0; k0 < K; k0 += 32) {
        __syncthreads();   // previous compute done reading LDS
        // A tile: 128 rows x 32 bf16 = 512 x 16B chunks; chunk c -> row=c>>2, q=c&3
#pragma unroll
        for (int it = 0; it < 2; ++it) {
            int c = tid + it * 256;
            int row = c >> 2, q = c & 3;
            __builtin_amdgcn_global_load_lds(
                GLP(Abf + (size_t)(m0 + row) * K + k0 + q * 8),
                LDSP(&Al[c * 8]), 16, 0, 0);
        }
#pragma unroll
        for (int it = 0; it < 2; ++it) {
            int c = tid + it * 256;
            int row = c >> 2, q = c & 3;
            __builtin_amdgcn_global_load_lds(
                GLP(Bt + (size_t)(n0 + row) * K + k0 + q * 8),
                LDSP(&Bl[c * 8]), 16, 0, 0);
        }
        __syncthreads();   // compiler drains vmcnt(0) before this barrier

        bf16x8 af[4], bfr[4];
#pragma unroll
        for (int i = 0; i < 4; ++i) af[i]  = *(const bf16x8*)&Al[(wm_ + i * 16 + fr) * 32 + fk];
#pragma unroll
        for (int j = 0; j < 4; ++j) bfr[j] = *(const bf16x8*)&Bl[(wn_ + j * 16 + fr) * 32 + fk];
#pragma unroll
        for (int i = 0; i < 4; ++i)
#pragma unroll
            for (int j = 0; j < 4; ++j)
                acc[i][j] = __builtin_amdgcn_mfma_f32_16x16x32_bf16(af[i], bfr[j], acc[i][j], 0, 0, 0);
    }

    // epilogue: C = acc + bias   (C/D layout: col = lane&15, row = (lane>>4)*4 + r)
#pragma unroll
    for (int j = 0; j < 4; ++j) {
        int col = n0 + wn_ + j * 16 + (lane & 15);
        float bs = (col < nsplit) ? bias0[col] : bias1[col - nsplit];
#pragma unroll
        for (int i = 0; i < 4; ++i) {
            int rowb = m0 + wm_ + i * 16 + (lane >> 4) * 4;
#pragma unroll
            for (int r = 0; r < 4; ++r)
                C[(size_t)(rowb + r) * N + col] = acc[i][j][r] + bs;
        }
    }
}

// ---------- fallback GEMM (round-1, f32 A with inline cvt) ----------
__global__ __launch_bounds__(256) void gemm_fb(
    const float* __restrict__ A, const unsigned short* __restrict__ Bt,
    const float* __restrict__ bias0, const float* __restrict__ bias1, int nsplit,
    float* __restrict__ C, int M, int N, int K)
{
    const int tid = threadIdx.x, lane = tid & 63, wid = tid >> 6;
    const int m0 = blockIdx.x * 128, n0 = blockIdx.y * 128;
    __shared__ unsigned short Al[128 * 40];
    __shared__ unsigned short Bl[128 * 40];

    f32x4 acc[4][4];
#pragma unroll
    for (int i = 0; i < 4; ++i)
#pragma unroll
        for (int j = 0; j < 4; ++j) acc[i][j] = (f32x4){0.f, 0.f, 0.f, 0.f};

    const int wm_ = (wid >> 1) * 64, wn_ = (wid & 1) * 64;
    const int fr = lane & 15, fk = (lane >> 4) * 8;

    for (int k0 = 0; k0 < K; k0 += 32) {
        __syncthreads();
#pragma unroll
        for (int it = 0; it < 4; ++it) {
            int idx = tid + it * 256;
            int row = idx >> 3, c4 = idx & 7;
            float4 v = *(const float4*)(A + (size_t)(m0 + row) * K + k0 + c4 * 4);
            ushort4_t h;
            h.x = f2bf(v.x); h.y = f2bf(v.y); h.z = f2bf(v.z); h.w = f2bf(v.w);
            *(ushort4_t*)&Al[row * 40 + c4 * 4] = h;
        }
#pragma unroll
        for (int it = 0; it < 2; ++it) {
            int idx = tid + it * 256;
            int row = idx >> 2, c4 = idx & 3;
            uint4_t v = *(const uint4_t*)(Bt + (size_t)(n0 + row) * K + k0 + c4 * 8);
            *(uint4_t*)&Bl[row * 40 + c4 * 8] = v;
        }
        __syncthreads();

        bf16x8 af[4], bfr[4];
#pragma unroll
        for (int i = 0; i < 4; ++i) af[i]  = *(const bf16x8*)&Al[(wm_ + i * 16 + fr) * 40 + fk];
#pragma unroll
        for (int j = 0; j < 4; ++j) bfr[j] = *(const bf16x8*)&Bl[(wn_ + j * 16 + fr) * 40 + fk];
#pragma unroll
        for (int i = 0; i < 4; ++i)
#pragma unroll
            for (int j = 0; j < 4; ++j)
                acc[i][j] = __builtin_amdgcn_mfma_f32_16x16x32_bf16(af[i], bfr[j], acc[i][j], 0, 0, 0);
    }

#pragma unroll
    for (int j = 0; j < 4; ++j) {
        int col = n0 + wn_ + j * 16 + (lane & 15);
        float bs = (col < nsplit) ? bias0[col] : bias1[col - nsplit];
#pragma unroll
        for (int i = 0; i < 4; ++i) {
            int rowb = m0 + wm_ + i * 16 + (lane >> 4) * 4;
#pragma unroll
            for (int r = 0; r < 4; ++r)
                C[(size_t)(rowb + r) * N + col] = acc[i][j][r] + bs;
        }
    }
}

// ---------- wm kernel ----------
__global__ __launch_bounds__(256) void wm_kernel(
    const float* __restrict__ qf_g, const float* __restrict__ imgCE,
    const float* __restrict__ g1, const float* __restrict__ b1,
    float* __restrict__ wm_g)
{
    const int b = blockIdx.x, tid = threadIdx.x, lane = tid & 63, wid = tid >> 6;
    __shared__ float qf[14 * 768];
    __shared__ float wmr[14][100];

    const float4* src = (const float4*)(qf_g + (size_t)b * 14 * 768);
    for (int i = tid; i < 14 * 768 / 4; i += 256) ((float4*)qf)[i] = src[i];
    __syncthreads();

    for (int n = wid; n < 100; n += 4) {
        const float* row = imgCE + ((size_t)b * 100 + n) * 1536;
        float r[12];
#pragma unroll
        for (int j = 0; j < 12; ++j) r[j] = row[lane + 64 * j];
        for (int t = 0; t < 14; ++t) {
            const float* q = qf + t * 768;
            float s = 0.f;
#pragma unroll
            for (int j = 0; j < 12; ++j) s = fmaf(r[j], q[lane + 64 * j], s);
            s = wave_sum(s);
            if (lane == 0) wmr[t][n] = s;
        }
    }
    __syncthreads();

    for (int t = wid; t < 14; t += 4) {
        float x0 = wmr[t][lane];
        float x1 = (lane + 64 < 100) ? wmr[t][lane + 64] : 0.f;
        float s = wave_sum(x0 + x1);
        float q = wave_sum(x0 * x0 + x1 * x1);
        float mu = s * (1.f / 100.f);
        float var = q * (1.f / 100.f) - mu * mu;
        float rs = rsqrtf(var + 1e-3f);
        float* dst = wm_g + ((size_t)b * 14 + t) * 100;
        {
            float v = (x0 - mu) * rs * g1[lane] + b1[lane];
            dst[lane] = v > 0.f ? v : 0.f;
        }
        if (lane + 64 < 100) {
            float v = (x1 - mu) * rs * g1[lane + 64] + b1[lane + 64];
            dst[lane + 64] = v > 0.f ? v : 0.f;
        }
    }
}

// ---------- ques path ----------
__global__ __launch_bounds__(256) void ques_kernel(
    const float* __restrict__ qf_g, const float* __restrict__ qe_g,
    const float* __restrict__ imgCE, const float* __restrict__ wm_g,
    const float* __restrict__ g2, const float* __restrict__ b2,
    const float* __restrict__ g3, const float* __restrict__ b3,
    const float* __restrict__ wqa, const float* __restrict__ bqa,
    float* __restrict__ out_q)
{
    const int b = blockIdx.x, tid = threadIdx.x, lane = tid & 63, wid = tid >> 6;
    __shared__ float qe[14 * 768];
    __shared__ float wm[14 * 100];
    __shared__ float red[4][28];
    __shared__ float mu_s[14], rs_s[14], qa_s[14], qw_s[14];

    {
        const float4* src = (const float4*)(qe_g + (size_t)b * 14 * 768);
        for (int i = tid; i < 14 * 768 / 4; i += 256) ((float4*)qe)[i] = src[i];
        const float* ws = wm_g + (size_t)b * 1400;
        for (int i = tid; i < 1400; i += 256) wm[i] = ws[i];
    }
    __syncthreads();

    float a0[14], a1[14], a2[14];
#pragma unroll
    for (int t = 0; t < 14; ++t) { a0[t] = 0.f; a1[t] = 0.f; a2[t] = 0.f; }

    const float* ie_base = imgCE + (size_t)b * 100 * 1536 + 768;
    for (int n = 0; n < 100; ++n) {
        const float* ie = ie_base + (size_t)n * 1536;
        float e0 = ie[tid], e1 = ie[tid + 256], e2 = ie[tid + 512];
#pragma unroll
        for (int t = 0; t < 14; ++t) {
            float w = wm[t * 100 + n];
            a0[t] = fmaf(w, e0, a0[t]); a1[t] = fmaf(w, e1, a1[t]); a2[t] = fmaf(w, e2, a2[t]);
        }
    }
#pragma unroll
    for (int t = 0; t < 14; ++t) {
        a0[t] += qe[t * 768 + tid];
        a1[t] += qe[t * 768 + tid + 256];
        a2[t] += qe[t * 768 + tid + 512];
    }
#pragma unroll
    for (int t = 0; t < 14; ++t) {
        float s = wave_sum(a0[t] + a1[t] + a2[t]);
        float q = wave_sum(a0[t] * a0[t] + a1[t] * a1[t] + a2[t] * a2[t]);
        if (lane == 0) { red[wid][t] = s; red[wid][14 + t] = q; }
    }
    __syncthreads();
    if (tid < 14) {
        float s = red[0][tid] + red[1][tid] + red[2][tid] + red[3][tid];
        float q = red[0][14 + tid] + red[1][14 + tid] + red[2][14 + tid] + red[3][14 + tid];
        float mu = s * (1.f / 768.f);
        float var = q * (1.f / 768.f) - mu * mu;
        mu_s[tid] = mu; rs_s[tid] = rsqrtf(var + 1e-3f);
    }
    __syncthreads();

    float ga = g2[tid], ba = b2[tid], gb = g2[tid + 256], bb = b2[tid + 256],
          gc = g2[tid + 512], bc_ = b2[tid + 512];
    float w0 = wqa[tid], w1 = wqa[tid + 256], w2 = wqa[tid + 512];
#pragma unroll
    for (int t = 0; t < 14; ++t) {
        float mu = mu_s[t], rs = rs_s[t];
        float v0 = fmaxf((a0[t] - mu) * rs * ga + ba, 0.f);
        float v1 = fmaxf((a1[t] - mu) * rs * gb + bb, 0.f);
        float v2 = fmaxf((a2[t] - mu) * rs * gc + bc_, 0.f);
        float p = wave_sum(v0 * w0 + v1 * w1 + v2 * w2);
        if (lane == 0) red[wid][t] = p;
    }
    __syncthreads();
    if (tid < 14) qa_s[tid] = red[0][tid] + red[1][tid] + red[2][tid] + red[3][tid] + bqa[0];
    __syncthreads();
    if (tid == 0) {
        float s = 0.f;
        for (int t = 0; t < 14; ++t) s += qa_s[t];
        float mu = s * (1.f / 14.f);
        float q = 0.f;
        for (int t = 0; t < 14; ++t) { float d = qa_s[t] - mu; q += d * d; }
        float rs = rsqrtf(q * (1.f / 14.f) + 1e-3f);
        float e[14], mx = -1e30f;
        for (int t = 0; t < 14; ++t) { e[t] = (qa_s[t] - mu) * rs * g3[t] + b3[t]; mx = fmaxf(mx, e[t]); }
        float se = 0.f;
        for (int t = 0; t < 14; ++t) { e[t] = expf(e[t] - mx); se += e[t]; }
        float inv = 1.f / se;
        for (int t = 0; t < 14; ++t) qw_s[t] = e[t] * inv;
    }
    __syncthreads();

    const float* qf = qf_g + (size_t)b * 14 * 768;
#pragma unroll
    for (int c = 0; c < 3; ++c) {
        int h = tid + c * 256;
        float o = 0.f;
#pragma unroll
        for (int t = 0; t < 14; ++t) o = fmaf(qw_s[t], qf[t * 768 + h], o);
        out_q[(size_t)b * 768 + h] = o;
    }
}

// ---------- img path ----------
__global__ __launch_bounds__(256) void img_kernel(
    const float* __restrict__ img_feat, const float* __restrict__ qe_g,
    const float* __restrict__ imgCE, const float* __restrict__ wm_g,
    const float* __restrict__ g4, const float* __restrict__ b4,
    const float* __restrict__ g5, const float* __restrict__ b5,
    const float* __restrict__ wia, const float* __restrict__ bia,
    float* __restrict__ out_i)
{
    const int b = blockIdx.x, tid = threadIdx.x, lane = tid & 63, wid = tid >> 6;
    __shared__ float qe[14 * 768];
    __shared__ float wm[14 * 100];
    __shared__ float red[4][20];
    __shared__ float mu_s[10], rs_s[10];
    __shared__ float ia_s[100], iw_s[100];

    {
        const float4* src = (const float4*)(qe_g + (size_t)b * 14 * 768);
        for (int i = tid; i < 14 * 768 / 4; i += 256) ((float4*)qe)[i] = src[i];
        const float* ws = wm_g + (size_t)b * 1400;
        for (int i = tid; i < 1400; i += 256) wm[i] = ws[i];
    }
    __syncthreads();

    float g4a = g4[tid], b4a = b4[tid], g4b = g4[tid + 256], b4b = b4[tid + 256],
          g4c = g4[tid + 512], b4c = b4[tid + 512];
    float wa = wia[tid], wb = wia[tid + 256], wc_ = wia[tid + 512];

    for (int g = 0; g < 10; ++g) {
        float t0[10], t1[10], t2[10];
#pragma unroll
        for (int i = 0; i < 10; ++i) { t0[i] = 0.f; t1[i] = 0.f; t2[i] = 0.f; }
#pragma unroll
        for (int t = 0; t < 14; ++t) {
            float q0 = qe[t * 768 + tid], q1 = qe[t * 768 + tid + 256], q2 = qe[t * 768 + tid + 512];
#pragma unroll
            for (int i = 0; i < 10; ++i) {
                float w = wm[t * 100 + g * 10 + i];
                t0[i] = fmaf(w, q0, t0[i]); t1[i] = fmaf(w, q1, t1[i]); t2[i] = fmaf(w, q2, t2[i]);
            }
        }
#pragma unroll
        for (int i = 0; i < 10; ++i) {
            const float* ie = imgCE + ((size_t)b * 100 + g * 10 + i) * 1536 + 768;
            t0[i] += ie[tid]; t1[i] += ie[tid + 256]; t2[i] += ie[tid + 512];
            float s = wave_sum(t0[i] + t1[i] + t2[i]);
            float q = wave_sum(t0[i] * t0[i] + t1[i] * t1[i] + t2[i] * t2[i]);
            if (lane == 0) { red[wid][i] = s; red[wid][10 + i] = q; }
        }
        __syncthreads();
        if (tid < 10) {
            float s = red[0][tid] + red[1][tid] + red[2][tid] + red[3][tid];
            float q = red[0][10 + tid] + red[1][10 + tid] + red[2][10 + tid] + red[3][10 + tid];
            float mu = s * (1.f / 768.f);
            float var = q * (1.f / 768.f) - mu * mu;
            mu_s[tid] = mu; rs_s[tid] = rsqrtf(var + 1e-3f);
        }
        __syncthreads();
#pragma unroll
        for (int i = 0; i < 10; ++i) {
            float mu = mu_s[i], rs = rs_s[i];
            float v0 = fmaxf((t0[i] - mu) * rs * g4a + b4a, 0.f);
            float v1 = fmaxf((t1[i] - mu) * rs * g4b + b4b, 0.f);
            float v2 = fmaxf((t2[i] - mu) * rs * g4c + b4c, 0.f);
            float p = wave_sum(v0 * wa + v1 * wb + v2 * wc_);
            if (lane == 0) red[wid][i] = p;
        }
        __syncthreads();
        if (tid < 10) ia_s[g * 10 + tid] = red[0][tid] + red[1][tid] + red[2][tid] + red[3][tid] + bia[0];
        __syncthreads();
    }

    if (wid == 0) {
        float x0 = ia_s[lane];
        float x1 = (lane + 64 < 100) ? ia_s[lane + 64] : 0.f;
        float s = wave_sum(x0 + x1);
        float q = wave_sum(x0 * x0 + x1 * x1);
        float mu = s * 0.01f;
        float var = q * 0.01f - mu * mu;
        float rs = rsqrtf(var + 1e-3f);
        float v0 = (x0 - mu) * rs * g5[lane] + b5[lane];
        float v1 = (lane + 64 < 100) ? (x1 - mu) * rs * g5[lane + 64] + b5[lane + 64] : -1e30f;
        float mx = wave_max(fmaxf(v0, v1));
        float e0 = expf(v0 - mx);
        float e1 = (lane + 64 < 100) ? expf(v1 - mx) : 0.f;
        float se = wave_sum(e0 + e1);
        float inv = 1.f / se;
        iw_s[lane] = e0 * inv;
        if (lane + 64 < 100) iw_s[lane + 64] = e1 * inv;
    }
    __syncthreads();

    const float* imf = img_feat + (size_t)b * 100 * 2048;
#pragma unroll
    for (int c = 0; c < 2; ++c) {
        int col = tid + c * 256;
        float4 acc = {0.f, 0.f, 0.f, 0.f};
        for (int n = 0; n < 100; ++n) {
            float4 v = ((const float4*)(imf + (size_t)n * 2048))[col];
            float w = iw_s[n];
            acc.x = fmaf(w, v.x, acc.x); acc.y = fmaf(w, v.y, acc.y);
            acc.z = fmaf(w, v.z, acc.z); acc.w = fmaf(w, v.w, acc.w);
        }
        ((float4*)(out_i + (size_t)b * 2048))[col] = acc;
    }
}

// ---------- launch ----------
extern "C" void kernel_launch(void* const* d_in, const int* in_sizes, int n_in,
                              void* d_out, int out_size, void* d_ws, size_t ws_size,
                              hipStream_t stream)
{
    const float* img_feat = (const float*)d_in[0];
    const float* ques_feat = (const float*)d_in[1];
    const float* Wc = (const float*)d_in[2];
    const float* bc = (const float*)d_in[3];
    const float* Wq = (const float*)d_in[4];
    const float* bq = (const float*)d_in[5];
    const float* Wi = (const float*)d_in[6];
    const float* bi = (const float*)d_in[7];
    const float* wqa = (const float*)d_in[8];
    const float* bqa = (const float*)d_in[9];
    const float* wia = (const float*)d_in[10];
    const float* bia = (const float*)d_in[11];
    const float* g1 = (const float*)d_in[12]; const float* b1 = (const float*)d_in[13];
    const float* g2 = (const float*)d_in[14]; const float* b2 = (const float*)d_in[15];
    const float* g3 = (const float*)d_in[16]; const float* b3 = (const float*)d_in[17];
    const float* g4 = (const float*)d_in[18]; const float* b4 = (const float*)d_in[19];
    const float* g5 = (const float*)d_in[20]; const float* b5 = (const float*)d_in[21];

    // workspace layout (bytes)
    const size_t SZ_WP   = 1536u * 2048u * 2u;        //   6,291,456
    const size_t SZ_WQT  = 768u * 768u * 2u;          //   1,179,648
    const size_t SZ_IMG  = 51200ull * 1536u * 4u;     // 314,572,800
    const size_t SZ_QE   = 7168u * 768u * 4u;         //  22,020,096
    const size_t SZ_WM   = 512u * 1400u * 4u;         //   2,867,200
    const size_t SZ_ABF  = 51200ull * 2048u * 2u;     // 209,715,200
    const size_t SZ_QBF  = 7168u * 768u * 2u;         //  11,010,048

    const size_t OFF_WP  = 0;
    const size_t OFF_WQT = OFF_WP + SZ_WP;
    const size_t OFF_IMG = OFF_WQT + SZ_WQT;
    const size_t OFF_QE  = OFF_IMG + SZ_IMG;
    const size_t OFF_WM  = OFF_QE + SZ_QE;
    const size_t OFF_ABF = OFF_WM + SZ_WM;
    const size_t OFF_QBF = OFF_ABF + SZ_ABF;
    const size_t NEED_FB  = OFF_ABF;                  // ~347 MB (round-1 path)
    const size_t NEED_NEW = OFF_QBF + SZ_QBF;         // ~568 MB

    if (ws_size < NEED_FB) return;

    char* ws = (char*)d_ws;
    unsigned short* Wp  = (unsigned short*)(ws + OFF_WP);
    unsigned short* Wqt = (unsigned short*)(ws + OFF_WQT);
    float* imgCE = (float*)(ws + OFF_IMG);
    float* qe    = (float*)(ws + OFF_QE);
    float* wm    = (float*)(ws + OFF_WM);

    float* out_img = (float*)d_out;                   // [512][2048]
    float* out_q   = (float*)d_out + 512 * 2048;      // [512][768]

    hipLaunchKernelGGL(pack_w,  dim3(1536, 8), dim3(256), 0, stream, Wc, Wi, Wp);
    hipLaunchKernelGGL(pack_wq, dim3(768, 3),  dim3(256), 0, stream, Wq, Wqt);

    if (ws_size >= NEED_NEW) {
        unsigned short* Abf = (unsigned short*)(ws + OFF_ABF);
        unsigned short* Qbf = (unsigned short*)(ws + OFF_QBF);
        hipLaunchKernelGGL(cvt_bf16, dim3(2048), dim3(256), 0, stream,
                           img_feat, Abf, (long)(51200ull * 2048u / 8u));
        hipLaunchKernelGGL(cvt_bf16, dim3(1024), dim3(256), 0, stream,
                           ques_feat, Qbf, (long)(7168u * 768u / 8u));
        // imgCE = img_feat @ [Wc|Wi] + [bc|bi]   (M=51200, N=1536, K=2048), n-fastest grid
        hipLaunchKernelGGL(gemm_lds, dim3(12, 400), dim3(256), 0, stream,
                           Abf, Wp, bc, bi, 768, imgCE, 51200, 1536, 2048);
        // qe = ques_feat @ Wq + bq               (M=7168, N=768, K=768)
        hipLaunchKernelGGL(gemm_lds, dim3(6, 56), dim3(256), 0, stream,
                           Qbf, Wqt, bq, bq, 768, qe, 7168, 768, 768);
    } else {
        hipLaunchKernelGGL(gemm_fb, dim3(400, 12), dim3(256), 0, stream,
                           img_feat, Wp, bc, bi, 768, imgCE, 51200, 1536, 2048);
        hipLaunchKernelGGL(gemm_fb, dim3(56, 6), dim3(256), 0, stream,
                           ques_feat, Wqt, bq, bq, 768, qe, 7168, 768, 768);
    }

    hipLaunchKernelGGL(wm_kernel, dim3(512), dim3(256), 0, stream,
                       ques_feat, imgCE, g1, b1, wm);
    hipLaunchKernelGGL(ques_kernel, dim3(512), dim3(256), 0, stream,
                       ques_feat, qe, imgCE, wm, g2, b2, g3, b3, wqa, bqa, out_q);
    hipLaunchKernelGGL(img_kernel, dim3(512), dim3(256), 0, stream,
                       img_feat, qe, imgCE, wm, g4, b4, g5, b5, wia, bia, out_img);
}

// Round 3
// 890.924 us; speedup vs baseline: 1.4258x; 1.0942x over previous
//
#include <hip/hip_runtime.h>

// ---------- types & helpers ----------
using f32x4     = __attribute__((ext_vector_type(4))) float;
using bf16x8    = __attribute__((ext_vector_type(8))) short;
using ushort4_t = __attribute__((ext_vector_type(4))) unsigned short;
using ushort8_t = __attribute__((ext_vector_type(8))) unsigned short;
using uint4_t   = __attribute__((ext_vector_type(4))) unsigned int;

__device__ __forceinline__ unsigned short f2bf(float f) {
    unsigned u = __builtin_bit_cast(unsigned, f);
    u += 0x7fffu + ((u >> 16) & 1u);   // RNE
    return (unsigned short)(u >> 16);
}

__device__ __forceinline__ float wave_sum(float v) {
#pragma unroll
    for (int off = 32; off > 0; off >>= 1) v += __shfl_xor(v, off, 64);
    return v;
}
__device__ __forceinline__ float wave_max(float v) {
#pragma unroll
    for (int off = 32; off > 0; off >>= 1) v = fmaxf(v, __shfl_xor(v, off, 64));
    return v;
}

#define GLP(p)  ((const __attribute__((address_space(1))) void*)(p))
#define LDSP(p) ((__attribute__((address_space(3))) void*)(p))

// ---------- f32 -> bf16 bulk convert ----------
__global__ __launch_bounds__(256) void cvt_bf16(const float* __restrict__ in,
                                                unsigned short* __restrict__ out, long n8) {
    long i = (long)blockIdx.x * 256 + threadIdx.x;
    long stride = (long)gridDim.x * 256;
    for (; i < n8; i += stride) {
        const float4* p = (const float4*)(in + i * 8);
        float4 a = p[0], b = p[1];
        ushort8_t v;
        v[0] = f2bf(a.x); v[1] = f2bf(a.y); v[2] = f2bf(a.z); v[3] = f2bf(a.w);
        v[4] = f2bf(b.x); v[5] = f2bf(b.y); v[6] = f2bf(b.z); v[7] = f2bf(b.w);
        *(ushort8_t*)(out + i * 8) = v;
    }
}

// ---------- weight pack (transpose -> bf16, [N][K] row-major) ----------
__global__ void pack_w(const float* __restrict__ Wc, const float* __restrict__ Wi,
                       unsigned short* __restrict__ Wp) {
    int n = blockIdx.x, k = blockIdx.y * 256 + threadIdx.x;
    float v = (n < 768) ? Wc[(size_t)k * 768 + n] : Wi[(size_t)k * 768 + (n - 768)];
    Wp[(size_t)n * 2048 + k] = f2bf(v);
}

__global__ void pack_wq(const float* __restrict__ Wq, unsigned short* __restrict__ Wqt) {
    int n = blockIdx.x, k = blockIdx.y * 256 + threadIdx.x;
    Wqt[(size_t)n * 768 + k] = f2bf(Wq[(size_t)k * 768 + n]);
}

// ---------- 256x256 pipelined bf16 GEMM (T1+T2+T3+T4+T5) ----------
// C[M][N] = Abf[M][K] @ Bt[N][K]^T + bias.  BK=32, 8 waves (2Mx4N), 4-deep LDS pipeline.
// LDS chunk permutation: phys chunk c(r,s) = 4r + ((s + (r>>1))&3)  (16B chunks, 4 slots/row)
//  -> fragment reads (16 rows, fixed slot) hit 8 distinct bank-quads = 2-way = free.
//  gload_lds dest stays linear; global SOURCE is inverse-permuted (rule #21).
__global__ __launch_bounds__(512, 1) void gemm8(
    const unsigned short* __restrict__ A, const unsigned short* __restrict__ Bt,
    const float* __restrict__ bias0, const float* __restrict__ bias1, int nsplit,
    float* __restrict__ C, int N, int K, int NTN)
{
    __shared__ unsigned short LA[4][8192];   // 4 bufs x 256 rows x 32 bf16 (16KB)
    __shared__ unsigned short LB[4][8192];
    const int tid = threadIdx.x, lane = tid & 63, wid = tid >> 6;

    int nwg = (int)gridDim.x, bid = (int)blockIdx.x;
    if ((nwg & 7) == 0) { int cpx = nwg >> 3; bid = (bid & 7) * cpx + (bid >> 3); }  // T1
    const int tn = bid % NTN, tm = bid / NTN;
    const size_t m0 = (size_t)tm * 256, n0 = (size_t)tn * 256;
    const int NT = K >> 5;

    const int wr = wid >> 2, wc = wid & 3;
    const int wm = wr * 128, wn = wc * 64;
    const int fr = lane & 15, fs = lane >> 4;

    // staging: thread covers chunks c0=tid, c1=tid+512 of each 1024-chunk tile
    const int c0 = tid, c1 = tid + 512;
    const int r0 = c0 >> 2, s0 = ((c0 & 3) - (r0 >> 1)) & 3;
    const int r1 = c1 >> 2, s1 = ((c1 & 3) - (r1 >> 1)) & 3;
    const unsigned short* gA0 = A + (m0 + r0) * K + s0 * 8;
    const unsigned short* gA1 = A + (m0 + r1) * K + s1 * 8;
    const unsigned short* gB0 = Bt + (n0 + r0) * K + s0 * 8;
    const unsigned short* gB1 = Bt + (n0 + r1) * K + s1 * 8;

    // fragment LDS element offsets (loop-invariant)
    int offA[8], offB[4];
#pragma unroll
    for (int mf = 0; mf < 8; ++mf) {
        int r = wm + mf * 16 + fr;
        offA[mf] = (4 * r + ((fs + (r >> 1)) & 3)) * 8;
    }
#pragma unroll
    for (int nf = 0; nf < 4; ++nf) {
        int r = wn + nf * 16 + fr;
        offB[nf] = (4 * r + ((fs + (r >> 1)) & 3)) * 8;
    }

    f32x4 acc[8][4];
#pragma unroll
    for (int i = 0; i < 8; ++i)
#pragma unroll
        for (int j = 0; j < 4; ++j) acc[i][j] = (f32x4){0.f, 0.f, 0.f, 0.f};

    // prologue: stage tiles 0,1,2 (order per tile: A0,A1,B0,B1)
#pragma unroll
    for (int t = 0; t < 3; ++t) {
        if (t < NT) {
            __builtin_amdgcn_global_load_lds(GLP(gA0 + t * 32), LDSP(&LA[t][c0 * 8]), 16, 0, 0);
            __builtin_amdgcn_global_load_lds(GLP(gA1 + t * 32), LDSP(&LA[t][c1 * 8]), 16, 0, 0);
            __builtin_amdgcn_global_load_lds(GLP(gB0 + t * 32), LDSP(&LB[t][c0 * 8]), 16, 0, 0);
            __builtin_amdgcn_global_load_lds(GLP(gB1 + t * 32), LDSP(&LB[t][c1 * 8]), 16, 0, 0);
        }
    }

    for (int T = 0; T < NT; ++T) {
        const int buf = T & 3, pb = (T + 3) & 3;
        const int rem = NT - 1 - T;
        // gate: own loads for tile T landed (T4: counted, never 0 mid-loop)
        if (rem >= 2)      asm volatile("s_waitcnt vmcnt(8)" ::: "memory");
        else if (rem == 1) asm volatile("s_waitcnt vmcnt(4)" ::: "memory");
        else               asm volatile("s_waitcnt vmcnt(0)" ::: "memory");
        __builtin_amdgcn_s_barrier();           // all waves' tile-T loads landed
        __builtin_amdgcn_sched_barrier(0);

        bf16x8 av[4], bv[4];
        // ---- phase 1: M-half 0 x all N ----
#pragma unroll
        for (int mf = 0; mf < 4; ++mf) av[mf] = *(const bf16x8*)&LA[buf][offA[mf]];
#pragma unroll
        for (int nf = 0; nf < 4; ++nf) bv[nf] = *(const bf16x8*)&LB[buf][offB[nf]];
        if (T + 3 < NT) {
            __builtin_amdgcn_global_load_lds(GLP(gA0 + (size_t)(T + 3) * 32), LDSP(&LA[pb][c0 * 8]), 16, 0, 0);
            __builtin_amdgcn_global_load_lds(GLP(gA1 + (size_t)(T + 3) * 32), LDSP(&LA[pb][c1 * 8]), 16, 0, 0);
        }
        asm volatile("s_waitcnt lgkmcnt(0)" ::: "memory");
        __builtin_amdgcn_sched_barrier(0);      // rule #18
        __builtin_amdgcn_s_setprio(1);
#pragma unroll
        for (int mf = 0; mf < 4; ++mf)
#pragma unroll
            for (int nf = 0; nf < 4; ++nf)
                acc[mf][nf] = __builtin_amdgcn_mfma_f32_16x16x32_bf16(av[mf], bv[nf], acc[mf][nf], 0, 0, 0);
        __builtin_amdgcn_s_setprio(0);

        // ---- phase 2: M-half 1 x all N (B reused in regs) ----
#pragma unroll
        for (int mf = 0; mf < 4; ++mf) av[mf] = *(const bf16x8*)&LA[buf][offA[4 + mf]];
        if (T + 3 < NT) {
            __builtin_amdgcn_global_load_lds(GLP(gB0 + (size_t)(T + 3) * 32), LDSP(&LB[pb][c0 * 8]), 16, 0, 0);
            __builtin_amdgcn_global_load_lds(GLP(gB1 + (size_t)(T + 3) * 32), LDSP(&LB[pb][c1 * 8]), 16, 0, 0);
        }
        asm volatile("s_waitcnt lgkmcnt(0)" ::: "memory");
        __builtin_amdgcn_sched_barrier(0);
        __builtin_amdgcn_s_setprio(1);
#pragma unroll
        for (int mf = 0; mf < 4; ++mf)
#pragma unroll
            for (int nf = 0; nf < 4; ++nf)
                acc[4 + mf][nf] = __builtin_amdgcn_mfma_f32_16x16x32_bf16(av[mf], bv[nf], acc[4 + mf][nf], 0, 0, 0);
        __builtin_amdgcn_s_setprio(0);
    }

    // epilogue  (C/D layout: col = lane&15, row = (lane>>4)*4 + r)
#pragma unroll
    for (int nf = 0; nf < 4; ++nf) {
        int col = (int)n0 + wn + nf * 16 + fr;
        float bs = (col < nsplit) ? bias0[col] : bias1[col - nsplit];
#pragma unroll
        for (int mf = 0; mf < 8; ++mf) {
            size_t rowb = m0 + wm + mf * 16 + fs * 4;
#pragma unroll
            for (int r = 0; r < 4; ++r)
                C[(rowb + r) * N + col] = acc[mf][nf][r] + bs;
        }
    }
}

// ---------- fallback GEMM (f32 A with inline cvt, small-ws path) ----------
__global__ __launch_bounds__(256) void gemm_fb(
    const float* __restrict__ A, const unsigned short* __restrict__ Bt,
    const float* __restrict__ bias0, const float* __restrict__ bias1, int nsplit,
    float* __restrict__ C, int M, int N, int K)
{
    const int tid = threadIdx.x, lane = tid & 63, wid = tid >> 6;
    const int m0 = blockIdx.x * 128, n0 = blockIdx.y * 128;
    __shared__ unsigned short Al[128 * 40];
    __shared__ unsigned short Bl[128 * 40];

    f32x4 acc[4][4];
#pragma unroll
    for (int i = 0; i < 4; ++i)
#pragma unroll
        for (int j = 0; j < 4; ++j) acc[i][j] = (f32x4){0.f, 0.f, 0.f, 0.f};

    const int wm_ = (wid >> 1) * 64, wn_ = (wid & 1) * 64;
    const int fr = lane & 15, fk = (lane >> 4) * 8;

    for (int k0 = 0; k0 < K; k0 += 32) {
        __syncthreads();
#pragma unroll
        for (int it = 0; it < 4; ++it) {
            int idx = tid + it * 256;
            int row = idx >> 3, c4 = idx & 7;
            float4 v = *(const float4*)(A + (size_t)(m0 + row) * K + k0 + c4 * 4);
            ushort4_t h;
            h.x = f2bf(v.x); h.y = f2bf(v.y); h.z = f2bf(v.z); h.w = f2bf(v.w);
            *(ushort4_t*)&Al[row * 40 + c4 * 4] = h;
        }
#pragma unroll
        for (int it = 0; it < 2; ++it) {
            int idx = tid + it * 256;
            int row = idx >> 2, c4 = idx & 3;
            uint4_t v = *(const uint4_t*)(Bt + (size_t)(n0 + row) * K + k0 + c4 * 8);
            *(uint4_t*)&Bl[row * 40 + c4 * 8] = v;
        }
        __syncthreads();

        bf16x8 af[4], bfr[4];
#pragma unroll
        for (int i = 0; i < 4; ++i) af[i]  = *(const bf16x8*)&Al[(wm_ + i * 16 + fr) * 40 + fk];
#pragma unroll
        for (int j = 0; j < 4; ++j) bfr[j] = *(const bf16x8*)&Bl[(wn_ + j * 16 + fr) * 40 + fk];
#pragma unroll
        for (int i = 0; i < 4; ++i)
#pragma unroll
            for (int j = 0; j < 4; ++j)
                acc[i][j] = __builtin_amdgcn_mfma_f32_16x16x32_bf16(af[i], bfr[j], acc[i][j], 0, 0, 0);
    }

#pragma unroll
    for (int j = 0; j < 4; ++j) {
        int col = n0 + wn_ + j * 16 + (lane & 15);
        float bs = (col < nsplit) ? bias0[col] : bias1[col - nsplit];
#pragma unroll
        for (int i = 0; i < 4; ++i) {
            int rowb = m0 + wm_ + i * 16 + (lane >> 4) * 4;
#pragma unroll
            for (int r = 0; r < 4; ++r)
                C[(size_t)(rowb + r) * N + col] = acc[i][j][r] + bs;
        }
    }
}

// ---------- wm kernel ----------
__global__ __launch_bounds__(256) void wm_kernel(
    const float* __restrict__ qf_g, const float* __restrict__ imgCE,
    const float* __restrict__ g1, const float* __restrict__ b1,
    float* __restrict__ wm_g)
{
    const int b = blockIdx.x, tid = threadIdx.x, lane = tid & 63, wid = tid >> 6;
    __shared__ float qf[14 * 768];
    __shared__ float wmr[14][100];

    const float4* src = (const float4*)(qf_g + (size_t)b * 14 * 768);
    for (int i = tid; i < 14 * 768 / 4; i += 256) ((float4*)qf)[i] = src[i];
    __syncthreads();

    for (int n = wid; n < 100; n += 4) {
        const float* row = imgCE + ((size_t)b * 100 + n) * 1536;
        float r[12];
#pragma unroll
        for (int j = 0; j < 12; ++j) r[j] = row[lane + 64 * j];
        for (int t = 0; t < 14; ++t) {
            const float* q = qf + t * 768;
            float s = 0.f;
#pragma unroll
            for (int j = 0; j < 12; ++j) s = fmaf(r[j], q[lane + 64 * j], s);
            s = wave_sum(s);
            if (lane == 0) wmr[t][n] = s;
        }
    }
    __syncthreads();

    for (int t = wid; t < 14; t += 4) {
        float x0 = wmr[t][lane];
        float x1 = (lane + 64 < 100) ? wmr[t][lane + 64] : 0.f;
        float s = wave_sum(x0 + x1);
        float q = wave_sum(x0 * x0 + x1 * x1);
        float mu = s * (1.f / 100.f);
        float var = q * (1.f / 100.f) - mu * mu;
        float rs = rsqrtf(var + 1e-3f);
        float* dst = wm_g + ((size_t)b * 14 + t) * 100;
        {
            float v = (x0 - mu) * rs * g1[lane] + b1[lane];
            dst[lane] = v > 0.f ? v : 0.f;
        }
        if (lane + 64 < 100) {
            float v = (x1 - mu) * rs * g1[lane + 64] + b1[lane + 64];
            dst[lane + 64] = v > 0.f ? v : 0.f;
        }
    }
}

// ---------- ques path ----------
__global__ __launch_bounds__(256) void ques_kernel(
    const float* __restrict__ qf_g, const float* __restrict__ qe_g,
    const float* __restrict__ imgCE, const float* __restrict__ wm_g,
    const float* __restrict__ g2, const float* __restrict__ b2,
    const float* __restrict__ g3, const float* __restrict__ b3,
    const float* __restrict__ wqa, const float* __restrict__ bqa,
    float* __restrict__ out_q)
{
    const int b = blockIdx.x, tid = threadIdx.x, lane = tid & 63, wid = tid >> 6;
    __shared__ float qe[14 * 768];
    __shared__ float wm[14 * 100];
    __shared__ float red[4][28];
    __shared__ float mu_s[14], rs_s[14], qa_s[14], qw_s[14];

    {
        const float4* src = (const float4*)(qe_g + (size_t)b * 14 * 768);
        for (int i = tid; i < 14 * 768 / 4; i += 256) ((float4*)qe)[i] = src[i];
        const float* ws = wm_g + (size_t)b * 1400;
        for (int i = tid; i < 1400; i += 256) wm[i] = ws[i];
    }
    __syncthreads();

    float a0[14], a1[14], a2[14];
#pragma unroll
    for (int t = 0; t < 14; ++t) { a0[t] = 0.f; a1[t] = 0.f; a2[t] = 0.f; }

    const float* ie_base = imgCE + (size_t)b * 100 * 1536 + 768;
    for (int n = 0; n < 100; ++n) {
        const float* ie = ie_base + (size_t)n * 1536;
        float e0 = ie[tid], e1 = ie[tid + 256], e2 = ie[tid + 512];
#pragma unroll
        for (int t = 0; t < 14; ++t) {
            float w = wm[t * 100 + n];
            a0[t] = fmaf(w, e0, a0[t]); a1[t] = fmaf(w, e1, a1[t]); a2[t] = fmaf(w, e2, a2[t]);
        }
    }
#pragma unroll
    for (int t = 0; t < 14; ++t) {
        a0[t] += qe[t * 768 + tid];
        a1[t] += qe[t * 768 + tid + 256];
        a2[t] += qe[t * 768 + tid + 512];
    }
#pragma unroll
    for (int t = 0; t < 14; ++t) {
        float s = wave_sum(a0[t] + a1[t] + a2[t]);
        float q = wave_sum(a0[t] * a0[t] + a1[t] * a1[t] + a2[t] * a2[t]);
        if (lane == 0) { red[wid][t] = s; red[wid][14 + t] = q; }
    }
    __syncthreads();
    if (tid < 14) {
        float s = red[0][tid] + red[1][tid] + red[2][tid] + red[3][tid];
        float q = red[0][14 + tid] + red[1][14 + tid] + red[2][14 + tid] + red[3][14 + tid];
        float mu = s * (1.f / 768.f);
        float var = q * (1.f / 768.f) - mu * mu;
        mu_s[tid] = mu; rs_s[tid] = rsqrtf(var + 1e-3f);
    }
    __syncthreads();

    float ga = g2[tid], ba = b2[tid], gb = g2[tid + 256], bb = b2[tid + 256],
          gc = g2[tid + 512], bc_ = b2[tid + 512];
    float w0 = wqa[tid], w1 = wqa[tid + 256], w2 = wqa[tid + 512];
#pragma unroll
    for (int t = 0; t < 14; ++t) {
        float mu = mu_s[t], rs = rs_s[t];
        float v0 = fmaxf((a0[t] - mu) * rs * ga + ba, 0.f);
        float v1 = fmaxf((a1[t] - mu) * rs * gb + bb, 0.f);
        float v2 = fmaxf((a2[t] - mu) * rs * gc + bc_, 0.f);
        float p = wave_sum(v0 * w0 + v1 * w1 + v2 * w2);
        if (lane == 0) red[wid][t] = p;
    }
    __syncthreads();
    if (tid < 14) qa_s[tid] = red[0][tid] + red[1][tid] + red[2][tid] + red[3][tid] + bqa[0];
    __syncthreads();
    if (tid == 0) {
        float s = 0.f;
        for (int t = 0; t < 14; ++t) s += qa_s[t];
        float mu = s * (1.f / 14.f);
        float q = 0.f;
        for (int t = 0; t < 14; ++t) { float d = qa_s[t] - mu; q += d * d; }
        float rs = rsqrtf(q * (1.f / 14.f) + 1e-3f);
        float e[14], mx = -1e30f;
        for (int t = 0; t < 14; ++t) { e[t] = (qa_s[t] - mu) * rs * g3[t] + b3[t]; mx = fmaxf(mx, e[t]); }
        float se = 0.f;
        for (int t = 0; t < 14; ++t) { e[t] = expf(e[t] - mx); se += e[t]; }
        float inv = 1.f / se;
        for (int t = 0; t < 14; ++t) qw_s[t] = e[t] * inv;
    }
    __syncthreads();

    const float* qf = qf_g + (size_t)b * 14 * 768;
#pragma unroll
    for (int c = 0; c < 3; ++c) {
        int h = tid + c * 256;
        float o = 0.f;
#pragma unroll
        for (int t = 0; t < 14; ++t) o = fmaf(qw_s[t], qf[t * 768 + h], o);
        out_q[(size_t)b * 768 + h] = o;
    }
}

// ---------- img path ----------
__global__ __launch_bounds__(256) void img_kernel(
    const float* __restrict__ img_feat, const float* __restrict__ qe_g,
    const float* __restrict__ imgCE, const float* __restrict__ wm_g,
    const float* __restrict__ g4, const float* __restrict__ b4,
    const float* __restrict__ g5, const float* __restrict__ b5,
    const float* __restrict__ wia, const float* __restrict__ bia,
    float* __restrict__ out_i)
{
    const int b = blockIdx.x, tid = threadIdx.x, lane = tid & 63, wid = tid >> 6;
    __shared__ float qe[14 * 768];
    __shared__ float wm[14 * 100];
    __shared__ float red[4][20];
    __shared__ float mu_s[10], rs_s[10];
    __shared__ float ia_s[100], iw_s[100];

    {
        const float4* src = (const float4*)(qe_g + (size_t)b * 14 * 768);
        for (int i = tid; i < 14 * 768 / 4; i += 256) ((float4*)qe)[i] = src[i];
        const float* ws = wm_g + (size_t)b * 1400;
        for (int i = tid; i < 1400; i += 256) wm[i] = ws[i];
    }
    __syncthreads();

    float g4a = g4[tid], b4a = b4[tid], g4b = g4[tid + 256], b4b = b4[tid + 256],
          g4c = g4[tid + 512], b4c = b4[tid + 512];
    float wa = wia[tid], wb = wia[tid + 256], wc_ = wia[tid + 512];

    for (int g = 0; g < 10; ++g) {
        float t0[10], t1[10], t2[10];
#pragma unroll
        for (int i = 0; i < 10; ++i) { t0[i] = 0.f; t1[i] = 0.f; t2[i] = 0.f; }
#pragma unroll
        for (int t = 0; t < 14; ++t) {
            float q0 = qe[t * 768 + tid], q1 = qe[t * 768 + tid + 256], q2 = qe[t * 768 + tid + 512];
#pragma unroll
            for (int i = 0; i < 10; ++i) {
                float w = wm[t * 100 + g * 10 + i];
                t0[i] = fmaf(w, q0, t0[i]); t1[i] = fmaf(w, q1, t1[i]); t2[i] = fmaf(w, q2, t2[i]);
            }
        }
#pragma unroll
        for (int i = 0; i < 10; ++i) {
            const float* ie = imgCE + ((size_t)b * 100 + g * 10 + i) * 1536 + 768;
            t0[i] += ie[tid]; t1[i] += ie[tid + 256]; t2[i] += ie[tid + 512];
            float s = wave_sum(t0[i] + t1[i] + t2[i]);
            float q = wave_sum(t0[i] * t0[i] + t1[i] * t1[i] + t2[i] * t2[i]);
            if (lane == 0) { red[wid][i] = s; red[wid][10 + i] = q; }
        }
        __syncthreads();
        if (tid < 10) {
            float s = red[0][tid] + red[1][tid] + red[2][tid] + red[3][tid];
            float q = red[0][10 + tid] + red[1][10 + tid] + red[2][10 + tid] + red[3][10 + tid];
            float mu = s * (1.f / 768.f);
            float var = q * (1.f / 768.f) - mu * mu;
            mu_s[tid] = mu; rs_s[tid] = rsqrtf(var + 1e-3f);
        }
        __syncthreads();
#pragma unroll
        for (int i = 0; i < 10; ++i) {
            float mu = mu_s[i], rs = rs_s[i];
            float v0 = fmaxf((t0[i] - mu) * rs * g4a + b4a, 0.f);
            float v1 = fmaxf((t1[i] - mu) * rs * g4b + b4b, 0.f);
            float v2 = fmaxf((t2[i] - mu) * rs * g4c + b4c, 0.f);
            float p = wave_sum(v0 * wa + v1 * wb + v2 * wc_);
            if (lane == 0) red[wid][i] = p;
        }
        __syncthreads();
        if (tid < 10) ia_s[g * 10 + tid] = red[0][tid] + red[1][tid] + red[2][tid] + red[3][tid] + bia[0];
        __syncthreads();
    }

    if (wid == 0) {
        float x0 = ia_s[lane];
        float x1 = (lane + 64 < 100) ? ia_s[lane + 64] : 0.f;
        float s = wave_sum(x0 + x1);
        float q = wave_sum(x0 * x0 + x1 * x1);
        float mu = s * 0.01f;
        float var = q * 0.01f - mu * mu;
        float rs = rsqrtf(var + 1e-3f);
        float v0 = (x0 - mu) * rs * g5[lane] + b5[lane];
        float v1 = (lane + 64 < 100) ? (x1 - mu) * rs * g5[lane + 64] + b5[lane + 64] : -1e30f;
        float mx = wave_max(fmaxf(v0, v1));
        float e0 = expf(v0 - mx);
        float e1 = (lane + 64 < 100) ? expf(v1 - mx) : 0.f;
        float se = wave_sum(e0 + e1);
        float inv = 1.f / se;
        iw_s[lane] = e0 * inv;
        if (lane + 64 < 100) iw_s[lane + 64] = e1 * inv;
    }
    __syncthreads();

    const float* imf = img_feat + (size_t)b * 100 * 2048;
#pragma unroll
    for (int c = 0; c < 2; ++c) {
        int col = tid + c * 256;
        float4 acc = {0.f, 0.f, 0.f, 0.f};
        for (int n = 0; n < 100; ++n) {
            float4 v = ((const float4*)(imf + (size_t)n * 2048))[col];
            float w = iw_s[n];
            acc.x = fmaf(w, v.x, acc.x); acc.y = fmaf(w, v.y, acc.y);
            acc.z = fmaf(w, v.z, acc.z); acc.w = fmaf(w, v.w, acc.w);
        }
        ((float4*)(out_i + (size_t)b * 2048))[col] = acc;
    }
}

// ---------- launch ----------
extern "C" void kernel_launch(void* const* d_in, const int* in_sizes, int n_in,
                              void* d_out, int out_size, void* d_ws, size_t ws_size,
                              hipStream_t stream)
{
    const float* img_feat = (const float*)d_in[0];
    const float* ques_feat = (const float*)d_in[1];
    const float* Wc = (const float*)d_in[2];
    const float* bc = (const float*)d_in[3];
    const float* Wq = (const float*)d_in[4];
    const float* bq = (const float*)d_in[5];
    const float* Wi = (const float*)d_in[6];
    const float* bi = (const float*)d_in[7];
    const float* wqa = (const float*)d_in[8];
    const float* bqa = (const float*)d_in[9];
    const float* wia = (const float*)d_in[10];
    const float* bia = (const float*)d_in[11];
    const float* g1 = (const float*)d_in[12]; const float* b1 = (const float*)d_in[13];
    const float* g2 = (const float*)d_in[14]; const float* b2 = (const float*)d_in[15];
    const float* g3 = (const float*)d_in[16]; const float* b3 = (const float*)d_in[17];
    const float* g4 = (const float*)d_in[18]; const float* b4 = (const float*)d_in[19];
    const float* g5 = (const float*)d_in[20]; const float* b5 = (const float*)d_in[21];

    // workspace layout (bytes)
    const size_t SZ_WP   = 1536u * 2048u * 2u;
    const size_t SZ_WQT  = 768u * 768u * 2u;
    const size_t SZ_IMG  = 51200ull * 1536u * 4u;
    const size_t SZ_QE   = 7168u * 768u * 4u;
    const size_t SZ_WM   = 512u * 1400u * 4u;
    const size_t SZ_ABF  = 51200ull * 2048u * 2u;
    const size_t SZ_QBF  = 7168u * 768u * 2u;

    const size_t OFF_WP  = 0;
    const size_t OFF_WQT = OFF_WP + SZ_WP;
    const size_t OFF_IMG = OFF_WQT + SZ_WQT;
    const size_t OFF_QE  = OFF_IMG + SZ_IMG;
    const size_t OFF_WM  = OFF_QE + SZ_QE;
    const size_t OFF_ABF = OFF_WM + SZ_WM;
    const size_t OFF_QBF = OFF_ABF + SZ_ABF;
    const size_t NEED_FB  = OFF_ABF;
    const size_t NEED_NEW = OFF_QBF + SZ_QBF;

    if (ws_size < NEED_FB) return;

    char* ws = (char*)d_ws;
    unsigned short* Wp  = (unsigned short*)(ws + OFF_WP);
    unsigned short* Wqt = (unsigned short*)(ws + OFF_WQT);
    float* imgCE = (float*)(ws + OFF_IMG);
    float* qe    = (float*)(ws + OFF_QE);
    float* wm    = (float*)(ws + OFF_WM);

    float* out_img = (float*)d_out;                   // [512][2048]
    float* out_q   = (float*)d_out + 512 * 2048;      // [512][768]

    hipLaunchKernelGGL(pack_w,  dim3(1536, 8), dim3(256), 0, stream, Wc, Wi, Wp);
    hipLaunchKernelGGL(pack_wq, dim3(768, 3),  dim3(256), 0, stream, Wq, Wqt);

    if (ws_size >= NEED_NEW) {
        unsigned short* Abf = (unsigned short*)(ws + OFF_ABF);
        unsigned short* Qbf = (unsigned short*)(ws + OFF_QBF);
        hipLaunchKernelGGL(cvt_bf16, dim3(2048), dim3(256), 0, stream,
                           img_feat, Abf, (long)(51200ull * 2048u / 8u));
        hipLaunchKernelGGL(cvt_bf16, dim3(1024), dim3(256), 0, stream,
                           ques_feat, Qbf, (long)(7168u * 768u / 8u));
        // imgCE = img_feat @ [Wc|Wi] + [bc|bi]   (M=51200, N=1536, K=2048)
        hipLaunchKernelGGL(gemm8, dim3(1200), dim3(512), 0, stream,
                           Abf, Wp, bc, bi, 768, imgCE, 1536, 2048, 6);
        // qe = ques_feat @ Wq + bq               (M=7168, N=768, K=768)
        hipLaunchKernelGGL(gemm8, dim3(84), dim3(512), 0, stream,
                           Qbf, Wqt, bq, bq, 768, qe, 768, 768, 3);
    } else {
        hipLaunchKernelGGL(gemm_fb, dim3(400, 12), dim3(256), 0, stream,
                           img_feat, Wp, bc, bi, 768, imgCE, 51200, 1536, 2048);
        hipLaunchKernelGGL(gemm_fb, dim3(56, 6), dim3(256), 0, stream,
                           ques_feat, Wqt, bq, bq, 768, qe, 7168, 768, 768);
    }

    hipLaunchKernelGGL(wm_kernel, dim3(512), dim3(256), 0, stream,
                       ques_feat, imgCE, g1, b1, wm);
    hipLaunchKernelGGL(ques_kernel, dim3(512), dim3(256), 0, stream,
                       ques_feat, qe, imgCE, wm, g2, b2, g3, b3, wqa, bqa, out_q);
    hipLaunchKernelGGL(img_kernel, dim3(512), dim3(256), 0, stream,
                       img_feat, qe, imgCE, wm, g4, b4, g5, b5, wia, bia, out_img);
}